// Round 2
// baseline (17036.365 us; speedup 1.0000x reference)
//
#include <hip/hip_runtime.h>
#include <hip/hip_bf16.h>

// 4-layer GCN, N=100000 nodes, E=6400000 edges, dims 34->16->16->16->4.
//
// Factorization: norm[e] = dinv[src]*dinv[dst], so
//   out[i] = b + dinv[i] * sum_{e: dst=i} dinv[src]*h[src]   (incl. self-loop)
// => hp[j] = dinv[j]*(x[j]@W); agg[i] = hp[i] + sum_edges hp[src]; out = dinv*agg + b.
//
// NOTE: harness passes integer inputs as int32 (edge_index is int* here).

static constexpr int THREADS = 256;

// ---- degree / dinv --------------------------------------------------------

__global__ __launch_bounds__(THREADS)
void k_init_deg(int* __restrict__ deg, int n) {
    int i = blockIdx.x * THREADS + threadIdx.x;
    if (i < n) deg[i] = 1;  // self-loop
}

__global__ __launch_bounds__(THREADS)
void k_count_deg(const int* __restrict__ dst, int* __restrict__ deg, int e) {
    int i = blockIdx.x * THREADS + threadIdx.x;
    if (i >= e) return;
    atomicAdd(&deg[dst[i]], 1);
}

__global__ __launch_bounds__(THREADS)
void k_dinv(const int* __restrict__ deg, float* __restrict__ dinv, int n) {
    int i = blockIdx.x * THREADS + threadIdx.x;
    if (i < n) dinv[i] = 1.0f / sqrtf((float)deg[i]);
}

// ---- per-layer fused transform + tiny GEMM + self-loop init ---------------
// If TRANSFORM: xin = relu(dinv[i]*in[i] + bprev)  (in == agg of previous layer)
// hp[i] = dinv[i] * (xin @ W);  agg[i] = hp[i]  (self-loop contribution)

template<int DIN, int DOUT, bool TRANSFORM>
__global__ __launch_bounds__(THREADS)
void k_layer(const float* __restrict__ in, const float* __restrict__ W,
             const float* __restrict__ bprev, const float* __restrict__ dinv,
             float* __restrict__ hp, float* __restrict__ agg, int n) {
    __shared__ float sW[DIN * DOUT];
    for (int t = threadIdx.x; t < DIN * DOUT; t += THREADS) sW[t] = W[t];
    __syncthreads();

    int i = blockIdx.x * THREADS + threadIdx.x;
    if (i >= n) return;
    float di = dinv[i];

    float xin[DIN];
    if constexpr (DIN % 4 == 0) {
        const float4* in4 = (const float4*)(in + (size_t)i * DIN);
        #pragma unroll
        for (int k4 = 0; k4 < DIN / 4; k4++) {
            float4 v = in4[k4];
            xin[4 * k4 + 0] = v.x; xin[4 * k4 + 1] = v.y;
            xin[4 * k4 + 2] = v.z; xin[4 * k4 + 3] = v.w;
        }
    } else {
        #pragma unroll
        for (int k = 0; k < DIN; k++) xin[k] = in[(size_t)i * DIN + k];
    }
    if constexpr (TRANSFORM) {
        #pragma unroll
        for (int k = 0; k < DIN; k++)
            xin[k] = fmaxf(fmaf(di, xin[k], bprev[k]), 0.0f);
    }

    float acc[DOUT];
    #pragma unroll
    for (int j = 0; j < DOUT; j++) acc[j] = 0.0f;
    #pragma unroll
    for (int k = 0; k < DIN; k++) {
        float xk = xin[k];
        #pragma unroll
        for (int j = 0; j < DOUT; j++) acc[j] = fmaf(xk, sW[k * DOUT + j], acc[j]);
    }
    #pragma unroll
    for (int j = 0; j < DOUT; j++) acc[j] *= di;

    float4* hp4 = (float4*)(hp + (size_t)i * DOUT);
    float4* ag4 = (float4*)(agg + (size_t)i * DOUT);
    #pragma unroll
    for (int j4 = 0; j4 < DOUT / 4; j4++) {
        float4 v = make_float4(acc[4 * j4], acc[4 * j4 + 1], acc[4 * j4 + 2], acc[4 * j4 + 3]);
        hp4[j4] = v;
        ag4[j4] = v;
    }
}

// ---- edge scatter: agg[dst] += hp[src] ------------------------------------

template<int DOUT>
__global__ __launch_bounds__(THREADS)
void k_agg(const int* __restrict__ src, const int* __restrict__ dst,
           const float* __restrict__ hp, float* __restrict__ agg, int ecount) {
    int i = blockIdx.x * THREADS + threadIdx.x;
    if (i >= ecount) return;
    int s = src[i];
    int d = dst[i];
    const float4* s4 = (const float4*)(hp + (size_t)s * DOUT);
    float* dp = agg + (size_t)d * DOUT;
    #pragma unroll
    for (int j4 = 0; j4 < DOUT / 4; j4++) {
        float4 v = s4[j4];
        atomicAdd(dp + 4 * j4 + 0, v.x);
        atomicAdd(dp + 4 * j4 + 1, v.y);
        atomicAdd(dp + 4 * j4 + 2, v.z);
        atomicAdd(dp + 4 * j4 + 3, v.w);
    }
}

// ---- final: out = dinv*agg + b4 -------------------------------------------

__global__ __launch_bounds__(THREADS)
void k_final(const float* __restrict__ agg, const float* __restrict__ b4,
             const float* __restrict__ dinv, float* __restrict__ out, int n) {
    int i = blockIdx.x * THREADS + threadIdx.x;
    if (i >= n) return;
    float di = dinv[i];
    float4 a = *(const float4*)(agg + (size_t)i * 4);
    float4 o = make_float4(fmaf(di, a.x, b4[0]), fmaf(di, a.y, b4[1]),
                           fmaf(di, a.z, b4[2]), fmaf(di, a.w, b4[3]));
    *(float4*)(out + (size_t)i * 4) = o;
}

// ---------------------------------------------------------------------------

extern "C" void kernel_launch(void* const* d_in, const int* in_sizes, int n_in,
                              void* d_out, int out_size, void* d_ws, size_t ws_size,
                              hipStream_t stream) {
    const float* x   = (const float*)d_in[0];
    const int*   ei  = (const int*)d_in[1];   // int32 per harness conversion
    const float* W1  = (const float*)d_in[2];
    const float* b1  = (const float*)d_in[3];
    const float* W2  = (const float*)d_in[4];
    const float* b2  = (const float*)d_in[5];
    const float* W3  = (const float*)d_in[6];
    const float* b3  = (const float*)d_in[7];
    const float* W4  = (const float*)d_in[8];
    const float* b4  = (const float*)d_in[9];
    float*       out = (float*)d_out;

    const int N = in_sizes[0] / 34;
    const int E = in_sizes[1] / 2;
    const int* src = ei;
    const int* dst = ei + E;

    // workspace carve-out: deg + dinv + 3 rotating N*16 buffers (~20.8 MB)
    char* ws = (char*)d_ws;
    size_t off = 0;
    auto alloc = [&](size_t bytes) -> void* {
        void* p = ws + off;
        off += (bytes + 255) & ~(size_t)255;
        return p;
    };
    int*   deg  = (int*)  alloc((size_t)N * 4);
    float* dinv = (float*)alloc((size_t)N * 4);
    float* bufA = (float*)alloc((size_t)N * 16 * 4);
    float* bufB = (float*)alloc((size_t)N * 16 * 4);
    float* bufC = (float*)alloc((size_t)N * 16 * 4);

    const int gN = (N + THREADS - 1) / THREADS;
    const int gE = (E + THREADS - 1) / THREADS;

    // degree + dinv
    k_init_deg<<<gN, THREADS, 0, stream>>>(deg, N);
    k_count_deg<<<gE, THREADS, 0, stream>>>(dst, deg, E);
    k_dinv<<<gN, THREADS, 0, stream>>>(deg, dinv, N);

    // layer 1: x[34] -> 16      hp=bufA, agg=bufB
    k_layer<34, 16, false><<<gN, THREADS, 0, stream>>>(x, W1, nullptr, dinv, bufA, bufB, N);
    k_agg<16><<<gE, THREADS, 0, stream>>>(src, dst, bufA, bufB, E);

    // layer 2: 16 -> 16 (transform w/ b1)   in=bufB, hp=bufC, agg=bufA
    k_layer<16, 16, true><<<gN, THREADS, 0, stream>>>(bufB, W2, b1, dinv, bufC, bufA, N);
    k_agg<16><<<gE, THREADS, 0, stream>>>(src, dst, bufC, bufA, E);

    // layer 3: 16 -> 16 (b2)    in=bufA, hp=bufB, agg=bufC
    k_layer<16, 16, true><<<gN, THREADS, 0, stream>>>(bufA, W3, b2, dinv, bufB, bufC, N);
    k_agg<16><<<gE, THREADS, 0, stream>>>(src, dst, bufB, bufC, E);

    // layer 4: 16 -> 4 (b3)     in=bufC, hp=bufA, agg=bufB
    k_layer<16, 4, true><<<gN, THREADS, 0, stream>>>(bufC, W4, b3, dinv, bufA, bufB, N);
    k_agg<4><<<gE, THREADS, 0, stream>>>(src, dst, bufA, bufB, E);

    // epilogue: out = dinv*agg + b4
    k_final<<<gN, THREADS, 0, stream>>>(bufB, b4, dinv, out, N);
}

// Round 3
// 1073.427 us; speedup vs baseline: 15.8710x; 15.8710x over previous
//
#include <hip/hip_runtime.h>
#include <hip/hip_bf16.h>

// 4-layer GCN, N=100000 nodes, E=6400000 edges, dims 34->16->16->16->4.
//
// Factorization: norm[e] = dinv[src]*dinv[dst], so
//   out[i] = b + dinv[i] * sum_{e: dst=i} dinv[src]*h[src]   (incl. self-loop)
// => hp[j] = dinv[j]*(x[j]@W); agg[i] = hp[i] + sum_edges hp[src]; out = dinv*agg + b.
//
// Round-2 change: replace per-layer scatter atomics (34 B fabric traffic per
// 4 B atomic, ~5.2 ms/layer) with a CSR-by-dst built once per call, then
// atomic-free per-layer GATHER: 16-lane group per node, one 64 B line per edge.

static constexpr int THREADS = 256;

// ---- degree / dinv --------------------------------------------------------

__global__ __launch_bounds__(THREADS)
void k_zero(int* __restrict__ p, int n) {
    int i = blockIdx.x * THREADS + threadIdx.x;
    if (i < n) p[i] = 0;
}

__global__ __launch_bounds__(THREADS)
void k_count_deg(const int* __restrict__ dst, int* __restrict__ deg, int e) {
    int i = blockIdx.x * THREADS + threadIdx.x;
    if (i >= e) return;
    atomicAdd(&deg[dst[i]], 1);
}

// dinv = 1/sqrt(deg_edges + 1)  (+1 = self-loop)
__global__ __launch_bounds__(THREADS)
void k_dinv(const int* __restrict__ deg, float* __restrict__ dinv, int n) {
    int i = blockIdx.x * THREADS + threadIdx.x;
    if (i < n) dinv[i] = 1.0f / sqrtf((float)(deg[i] + 1));
}

// ---- exclusive scan over deg -> rowptr (3 kernels) ------------------------

__global__ __launch_bounds__(THREADS)
void k_scan1(const int* __restrict__ deg, int* __restrict__ rowptr,
             int* __restrict__ bsum, int n) {
    __shared__ int s[THREADS];
    int i = blockIdx.x * THREADS + threadIdx.x;
    int v = (i < n) ? deg[i] : 0;
    s[threadIdx.x] = v;
    __syncthreads();
    for (int ofs = 1; ofs < THREADS; ofs <<= 1) {
        int t = (threadIdx.x >= ofs) ? s[threadIdx.x - ofs] : 0;
        __syncthreads();
        s[threadIdx.x] += t;
        __syncthreads();
    }
    if (i < n) rowptr[i] = s[threadIdx.x] - v;  // exclusive within block
    if (threadIdx.x == THREADS - 1) bsum[blockIdx.x] = s[THREADS - 1];
}

__global__ __launch_bounds__(1024)
void k_scan2(int* __restrict__ bsum, int nb) {
    __shared__ int s[1024];
    int v = (threadIdx.x < nb) ? bsum[threadIdx.x] : 0;
    s[threadIdx.x] = v;
    __syncthreads();
    for (int ofs = 1; ofs < 1024; ofs <<= 1) {
        int t = (threadIdx.x >= ofs) ? s[threadIdx.x - ofs] : 0;
        __syncthreads();
        s[threadIdx.x] += t;
        __syncthreads();
    }
    if (threadIdx.x < nb) bsum[threadIdx.x] = s[threadIdx.x] - v;
}

__global__ __launch_bounds__(THREADS)
void k_scan3(int* __restrict__ rowptr, const int* __restrict__ bsum,
             int* __restrict__ cursor, int n, int e) {
    int i = blockIdx.x * THREADS + threadIdx.x;
    if (i < n) {
        int r = rowptr[i] + bsum[blockIdx.x];
        rowptr[i] = r;
        cursor[i] = r;
    }
    if (i == 0) rowptr[n] = e;
}

// ---- CSR fill -------------------------------------------------------------

__global__ __launch_bounds__(THREADS)
void k_fill(const int* __restrict__ src, const int* __restrict__ dst,
            int* __restrict__ cursor, int* __restrict__ csr, int e) {
    int i = blockIdx.x * THREADS + threadIdx.x;
    if (i >= e) return;
    int s = src[i];
    int d = dst[i];
    int pos = atomicAdd(&cursor[d], 1);
    csr[pos] = s;
}

// ---- per-layer fused transform + tiny GEMM --------------------------------
// If TRANSFORM: xin = relu(dinv[i]*in[i] + bprev)  (in == agg of previous layer)
// hp[i] = dinv[i] * (xin @ W)

template<int DIN, int DOUT, bool TRANSFORM>
__global__ __launch_bounds__(THREADS)
void k_layer(const float* __restrict__ in, const float* __restrict__ W,
             const float* __restrict__ bprev, const float* __restrict__ dinv,
             float* __restrict__ hp, int n) {
    __shared__ float sW[DIN * DOUT];
    for (int t = threadIdx.x; t < DIN * DOUT; t += THREADS) sW[t] = W[t];
    __syncthreads();

    int i = blockIdx.x * THREADS + threadIdx.x;
    if (i >= n) return;
    float di = dinv[i];

    float xin[DIN];
    if constexpr (DIN % 4 == 0) {
        const float4* in4 = (const float4*)(in + (size_t)i * DIN);
        #pragma unroll
        for (int k4 = 0; k4 < DIN / 4; k4++) {
            float4 v = in4[k4];
            xin[4 * k4 + 0] = v.x; xin[4 * k4 + 1] = v.y;
            xin[4 * k4 + 2] = v.z; xin[4 * k4 + 3] = v.w;
        }
    } else {
        #pragma unroll
        for (int k = 0; k < DIN; k++) xin[k] = in[(size_t)i * DIN + k];
    }
    if constexpr (TRANSFORM) {
        #pragma unroll
        for (int k = 0; k < DIN; k++)
            xin[k] = fmaxf(fmaf(di, xin[k], bprev[k]), 0.0f);
    }

    float acc[DOUT];
    #pragma unroll
    for (int j = 0; j < DOUT; j++) acc[j] = 0.0f;
    #pragma unroll
    for (int k = 0; k < DIN; k++) {
        float xk = xin[k];
        #pragma unroll
        for (int j = 0; j < DOUT; j++) acc[j] = fmaf(xk, sW[k * DOUT + j], acc[j]);
    }

    float4* hp4 = (float4*)(hp + (size_t)i * DOUT);
    #pragma unroll
    for (int j4 = 0; j4 < DOUT / 4; j4++)
        hp4[j4] = make_float4(acc[4 * j4] * di, acc[4 * j4 + 1] * di,
                              acc[4 * j4 + 2] * di, acc[4 * j4 + 3] * di);
}

// ---- atomic-free gather: agg[i] = hp[i] + sum_{e: dst=i} hp[src[e]] -------
// D lanes per node (D divides 64). Edge indices loaded D-at-a-time coalesced,
// broadcast via shfl; lane j accumulates channel j.

template<int D, bool FINAL>
__global__ __launch_bounds__(THREADS)
void k_gather(const int* __restrict__ rowptr, const int* __restrict__ csr,
              const float* __restrict__ hp, float* __restrict__ outp,
              const float* __restrict__ dinv, const float* __restrict__ bias,
              int n) {
    int tid  = blockIdx.x * THREADS + threadIdx.x;
    int row  = tid / D;
    int lane = tid & (D - 1);
    if (row >= n) return;
    int base = (threadIdx.x & 63) & ~(D - 1);  // wave-lane of group's lane 0

    int beg = rowptr[row];
    int end = rowptr[row + 1];

    float a0 = hp[(size_t)row * D + lane];  // self-loop
    float a1 = 0.f, a2 = 0.f, a3 = 0.f;

    int e = beg;
    for (; e + D <= end; e += D) {
        int s = csr[e + lane];
        #pragma unroll
        for (int k = 0; k < D; k += 4) {
            int s0 = __shfl(s, base + k + 0, 64);
            int s1 = __shfl(s, base + k + 1, 64);
            int s2 = __shfl(s, base + k + 2, 64);
            int s3 = __shfl(s, base + k + 3, 64);
            a0 += hp[(size_t)s0 * D + lane];
            a1 += hp[(size_t)s1 * D + lane];
            a2 += hp[(size_t)s2 * D + lane];
            a3 += hp[(size_t)s3 * D + lane];
        }
    }
    if (e < end) {
        int idx = e + lane;
        int s = (idx < end) ? csr[idx] : 0;
        int cnt = end - e;
        for (int k = 0; k < cnt; k++) {
            int sk = __shfl(s, base + k, 64);
            a0 += hp[(size_t)sk * D + lane];
        }
    }
    float acc = (a0 + a1) + (a2 + a3);

    if constexpr (FINAL) {
        outp[(size_t)row * D + lane] = fmaf(dinv[row], acc, bias[lane]);
    } else {
        outp[(size_t)row * D + lane] = acc;
    }
}

// ---- fallback scatter (if workspace too small for CSR) --------------------

template<int DOUT>
__global__ __launch_bounds__(THREADS)
void k_agg(const int* __restrict__ src, const int* __restrict__ dst,
           const float* __restrict__ hp, float* __restrict__ agg, int ecount) {
    int i = blockIdx.x * THREADS + threadIdx.x;
    if (i >= ecount) return;
    int s = src[i];
    int d = dst[i];
    const float4* s4 = (const float4*)(hp + (size_t)s * DOUT);
    float* dp = agg + (size_t)d * DOUT;
    #pragma unroll
    for (int j4 = 0; j4 < DOUT / 4; j4++) {
        float4 v = s4[j4];
        atomicAdd(dp + 4 * j4 + 0, v.x);
        atomicAdd(dp + 4 * j4 + 1, v.y);
        atomicAdd(dp + 4 * j4 + 2, v.z);
        atomicAdd(dp + 4 * j4 + 3, v.w);
    }
}

__global__ __launch_bounds__(THREADS)
void k_selfinit(const float* __restrict__ hp, float* __restrict__ agg, int n16) {
    int i = blockIdx.x * THREADS + threadIdx.x;
    if (i < n16) agg[i] = hp[i];
}

__global__ __launch_bounds__(THREADS)
void k_final(const float* __restrict__ agg, const float* __restrict__ b4,
             const float* __restrict__ dinv, float* __restrict__ out, int n) {
    int i = blockIdx.x * THREADS + threadIdx.x;
    if (i >= n) return;
    float di = dinv[i];
    float4 a = *(const float4*)(agg + (size_t)i * 4);
    *(float4*)(out + (size_t)i * 4) =
        make_float4(fmaf(di, a.x, b4[0]), fmaf(di, a.y, b4[1]),
                    fmaf(di, a.z, b4[2]), fmaf(di, a.w, b4[3]));
}

// ---------------------------------------------------------------------------

extern "C" void kernel_launch(void* const* d_in, const int* in_sizes, int n_in,
                              void* d_out, int out_size, void* d_ws, size_t ws_size,
                              hipStream_t stream) {
    const float* x   = (const float*)d_in[0];
    const int*   ei  = (const int*)d_in[1];   // int32 per harness conversion
    const float* W1  = (const float*)d_in[2];
    const float* b1  = (const float*)d_in[3];
    const float* W2  = (const float*)d_in[4];
    const float* b2  = (const float*)d_in[5];
    const float* W3  = (const float*)d_in[6];
    const float* b3  = (const float*)d_in[7];
    const float* W4  = (const float*)d_in[8];
    const float* b4  = (const float*)d_in[9];
    float*       out = (float*)d_out;

    const int N = in_sizes[0] / 34;
    const int E = in_sizes[1] / 2;
    const int* src = ei;
    const int* dst = ei + E;

    char* ws = (char*)d_ws;
    size_t off = 0;
    auto alloc = [&](size_t bytes) -> void* {
        void* p = ws + off;
        off += (bytes + 255) & ~(size_t)255;
        return p;
    };
    int*   deg    = (int*)  alloc((size_t)N * 4);
    float* dinv   = (float*)alloc((size_t)N * 4);
    float* bufA   = (float*)alloc((size_t)N * 16 * 4);
    float* bufB   = (float*)alloc((size_t)N * 16 * 4);
    float* bufC   = (float*)alloc((size_t)N * 16 * 4);
    size_t base_off = off;
    int*   rowptr = (int*)  alloc((size_t)(N + 1) * 4);
    int*   cursor = (int*)  alloc((size_t)N * 4);
    int*   csr    = (int*)  alloc((size_t)E * 4);
    bool   use_csr = off <= ws_size;
    (void)base_off;

    const int gN  = (N + THREADS - 1) / THREADS;        // node-grid (256/thread)
    const int gE  = (E + THREADS - 1) / THREADS;
    const int nb  = gN;                                  // blocks in scan1
    const int g16 = ((size_t)N * 16 + THREADS - 1) / THREADS;
    const int g4  = ((size_t)N * 4 + THREADS - 1) / THREADS;

    // degree (edges only; +1 self-loop folded into dinv)
    k_zero<<<gN, THREADS, 0, stream>>>(deg, N);
    k_count_deg<<<gE, THREADS, 0, stream>>>(dst, deg, E);
    k_dinv<<<gN, THREADS, 0, stream>>>(deg, dinv, N);

    if (use_csr) {
        // CSR by dst
        k_scan1<<<nb, THREADS, 0, stream>>>(deg, rowptr, cursor /*bsum scratch*/, N);
        // NOTE: bsum needs nb ints; reuse cursor[0..nb) temporarily is unsafe since
        // scan3 writes cursor — use deg? deg still needed? No: deg only feeds dinv
        // (done) and scan1 (done). Reuse deg as bsum would race scan1's reads.
        // cursor[0..nb) as bsum is fine: scan3 writes cursor AFTER reading bsum? It
        // reads bsum[blockIdx.x] then writes cursor[i] — same buffer, different
        // index ranges could collide (i in [0,N), bsum idx in [0,nb)). Unsafe.
        // => dedicated bsum carved below instead.
        (void)0;
    }

    if (use_csr) {
        // redo with a dedicated bsum buffer (carve after csr)
        int* bsum = (int*)alloc((size_t)nb * 4);
        use_csr = off <= ws_size;
        if (use_csr) {
            k_scan1<<<nb, THREADS, 0, stream>>>(deg, rowptr, bsum, N);
            k_scan2<<<1, 1024, 0, stream>>>(bsum, nb);
            k_scan3<<<nb, THREADS, 0, stream>>>(rowptr, bsum, cursor, N, E);
            k_fill<<<gE, THREADS, 0, stream>>>(src, dst, cursor, csr, E);

            // layer 1: x[34] -> 16      hp=A, agg=B
            k_layer<34, 16, false><<<gN, THREADS, 0, stream>>>(x, W1, nullptr, dinv, bufA, N);
            k_gather<16, false><<<(int)(((size_t)N * 16 + THREADS - 1) / THREADS), THREADS, 0, stream>>>(
                rowptr, csr, bufA, bufB, nullptr, nullptr, N);
            // layer 2: 16 -> 16 (b1)    in=B, hp=C, agg=A
            k_layer<16, 16, true><<<gN, THREADS, 0, stream>>>(bufB, W2, b1, dinv, bufC, N);
            k_gather<16, false><<<g16, THREADS, 0, stream>>>(rowptr, csr, bufC, bufA, nullptr, nullptr, N);
            // layer 3: 16 -> 16 (b2)    in=A, hp=B, agg=C
            k_layer<16, 16, true><<<gN, THREADS, 0, stream>>>(bufA, W3, b2, dinv, bufB, N);
            k_gather<16, false><<<g16, THREADS, 0, stream>>>(rowptr, csr, bufB, bufC, nullptr, nullptr, N);
            // layer 4: 16 -> 4 (b3)     in=C, hp=A; gather fuses out = dinv*agg + b4
            k_layer<16, 4, true><<<gN, THREADS, 0, stream>>>(bufC, W4, b3, dinv, bufA, N);
            k_gather<4, true><<<g4, THREADS, 0, stream>>>(rowptr, csr, bufA, out, dinv, b4, N);
            return;
        }
    }

    // ---- fallback: atomic scatter path (round-1 behavior) ----
    k_layer<34, 16, false><<<gN, THREADS, 0, stream>>>(x, W1, nullptr, dinv, bufA, N);
    k_selfinit<<<g16, THREADS, 0, stream>>>(bufA, bufB, N * 16);
    k_agg<16><<<gE, THREADS, 0, stream>>>(src, dst, bufA, bufB, E);

    k_layer<16, 16, true><<<gN, THREADS, 0, stream>>>(bufB, W2, b1, dinv, bufC, N);
    k_selfinit<<<g16, THREADS, 0, stream>>>(bufC, bufA, N * 16);
    k_agg<16><<<gE, THREADS, 0, stream>>>(src, dst, bufC, bufA, E);

    k_layer<16, 16, true><<<gN, THREADS, 0, stream>>>(bufA, W3, b2, dinv, bufB, N);
    k_selfinit<<<g16, THREADS, 0, stream>>>(bufB, bufC, N * 16);
    k_agg<16><<<gE, THREADS, 0, stream>>>(src, dst, bufB, bufC, E);

    k_layer<16, 4, true><<<gN, THREADS, 0, stream>>>(bufC, W4, b3, dinv, bufA, N);
    k_selfinit<<<g4, THREADS, 0, stream>>>(bufA, bufB, N * 4);
    k_agg<4><<<gE, THREADS, 0, stream>>>(src, dst, bufA, bufB, E);

    k_final<<<gN, THREADS, 0, stream>>>(bufB, b4, dinv, out, N);
}

// Round 4
// 615.851 us; speedup vs baseline: 27.6631x; 1.7430x over previous
//
#include <hip/hip_runtime.h>
#include <hip/hip_bf16.h>

// 4-layer GCN, N=100000, E=6400000, dims 34->16->16->16->4.
//
// out[i] = b + dinv[i] * sum_{e: dst=i} dinv[src]*h[src]  (incl. self-loop)
// => hp = dinv*(x@W); agg[i] = hp[i] + sum_{in-edges} hp[src]; out = dinv*agg + b.
//
// Round-3: CSR-by-dst + atomic-free per-layer gather (16 lanes/node).
// Round-4: single atomic pass. k_count_rank stores the atomicAdd return value
// (edge's rank within its dst); k_fill becomes atomic-free scattered stores.
// 4 edges/thread ILP on both edge passes.

static constexpr int THREADS = 256;
static constexpr int EPT = 4;  // edges per thread in edge passes

// ---- degree + rank --------------------------------------------------------

__global__ __launch_bounds__(THREADS)
void k_zero(int* __restrict__ p, int n) {
    int i = blockIdx.x * THREADS + threadIdx.x;
    if (i < n) p[i] = 0;
}

// rank[i] = old count of dst[i]; deg accumulates edge in-degree
__global__ __launch_bounds__(THREADS)
void k_count_rank(const int* __restrict__ dst, int* __restrict__ deg,
                  int* __restrict__ rank, int e) {
    int i = (blockIdx.x * THREADS + threadIdx.x) * EPT;
    if (i + EPT <= e) {
        int4 d = *(const int4*)(dst + i);
        int4 r;
        r.x = atomicAdd(&deg[d.x], 1);
        r.y = atomicAdd(&deg[d.y], 1);
        r.z = atomicAdd(&deg[d.z], 1);
        r.w = atomicAdd(&deg[d.w], 1);
        *(int4*)(rank + i) = r;
    } else {
        for (int k = i; k < e; k++) rank[k] = atomicAdd(&deg[dst[k]], 1);
    }
}

// scalar fallback (unaligned / cursor path)
__global__ __launch_bounds__(THREADS)
void k_count_deg(const int* __restrict__ dst, int* __restrict__ deg, int e) {
    int i = blockIdx.x * THREADS + threadIdx.x;
    if (i >= e) return;
    atomicAdd(&deg[dst[i]], 1);
}

// dinv = 1/sqrt(deg_edges + 1)  (+1 = self-loop)
__global__ __launch_bounds__(THREADS)
void k_dinv(const int* __restrict__ deg, float* __restrict__ dinv, int n) {
    int i = blockIdx.x * THREADS + threadIdx.x;
    if (i < n) dinv[i] = 1.0f / sqrtf((float)(deg[i] + 1));
}

// ---- exclusive scan over deg -> rowptr ------------------------------------

__global__ __launch_bounds__(THREADS)
void k_scan1(const int* __restrict__ deg, int* __restrict__ rowptr,
             int* __restrict__ bsum, int n) {
    __shared__ int s[THREADS];
    int i = blockIdx.x * THREADS + threadIdx.x;
    int v = (i < n) ? deg[i] : 0;
    s[threadIdx.x] = v;
    __syncthreads();
    for (int ofs = 1; ofs < THREADS; ofs <<= 1) {
        int t = (threadIdx.x >= ofs) ? s[threadIdx.x - ofs] : 0;
        __syncthreads();
        s[threadIdx.x] += t;
        __syncthreads();
    }
    if (i < n) rowptr[i] = s[threadIdx.x] - v;
    if (threadIdx.x == THREADS - 1) bsum[blockIdx.x] = s[THREADS - 1];
}

__global__ __launch_bounds__(1024)
void k_scan2(int* __restrict__ bsum, int nb) {
    __shared__ int s[1024];
    int v = (threadIdx.x < nb) ? bsum[threadIdx.x] : 0;
    s[threadIdx.x] = v;
    __syncthreads();
    for (int ofs = 1; ofs < 1024; ofs <<= 1) {
        int t = (threadIdx.x >= ofs) ? s[threadIdx.x - ofs] : 0;
        __syncthreads();
        s[threadIdx.x] += t;
        __syncthreads();
    }
    if (threadIdx.x < nb) bsum[threadIdx.x] = s[threadIdx.x] - v;
}

__global__ __launch_bounds__(THREADS)
void k_scan3(int* __restrict__ rowptr, const int* __restrict__ bsum,
             int* __restrict__ cursor, int n, int e) {
    int i = blockIdx.x * THREADS + threadIdx.x;
    if (i < n) {
        int r = rowptr[i] + bsum[blockIdx.x];
        rowptr[i] = r;
        cursor[i] = r;
    }
    if (i == 0) rowptr[n] = e;
}

// ---- CSR fill -------------------------------------------------------------

// atomic-free: pos = rowptr[dst] + rank
__global__ __launch_bounds__(THREADS)
void k_fill_rank(const int* __restrict__ src, const int* __restrict__ dst,
                 const int* __restrict__ rank, const int* __restrict__ rowptr,
                 int* __restrict__ csr, int e) {
    int i = (blockIdx.x * THREADS + threadIdx.x) * EPT;
    if (i + EPT <= e) {
        int4 s = *(const int4*)(src + i);
        int4 d = *(const int4*)(dst + i);
        int4 r = *(const int4*)(rank + i);
        csr[rowptr[d.x] + r.x] = s.x;
        csr[rowptr[d.y] + r.y] = s.y;
        csr[rowptr[d.z] + r.z] = s.z;
        csr[rowptr[d.w] + r.w] = s.w;
    } else {
        for (int k = i; k < e; k++) csr[rowptr[dst[k]] + rank[k]] = src[k];
    }
}

// cursor-atomic fallback (if rank buffer doesn't fit)
__global__ __launch_bounds__(THREADS)
void k_fill_cursor(const int* __restrict__ src, const int* __restrict__ dst,
                   int* __restrict__ cursor, int* __restrict__ csr, int e) {
    int i = blockIdx.x * THREADS + threadIdx.x;
    if (i >= e) return;
    int pos = atomicAdd(&cursor[dst[i]], 1);
    csr[pos] = src[i];
}

// ---- per-layer fused transform + tiny GEMM --------------------------------

template<int DIN, int DOUT, bool TRANSFORM>
__global__ __launch_bounds__(THREADS)
void k_layer(const float* __restrict__ in, const float* __restrict__ W,
             const float* __restrict__ bprev, const float* __restrict__ dinv,
             float* __restrict__ hp, int n) {
    __shared__ float sW[DIN * DOUT];
    for (int t = threadIdx.x; t < DIN * DOUT; t += THREADS) sW[t] = W[t];
    __syncthreads();

    int i = blockIdx.x * THREADS + threadIdx.x;
    if (i >= n) return;
    float di = dinv[i];

    float xin[DIN];
    if constexpr (DIN % 4 == 0) {
        const float4* in4 = (const float4*)(in + (size_t)i * DIN);
        #pragma unroll
        for (int k4 = 0; k4 < DIN / 4; k4++) {
            float4 v = in4[k4];
            xin[4 * k4 + 0] = v.x; xin[4 * k4 + 1] = v.y;
            xin[4 * k4 + 2] = v.z; xin[4 * k4 + 3] = v.w;
        }
    } else {
        #pragma unroll
        for (int k = 0; k < DIN; k++) xin[k] = in[(size_t)i * DIN + k];
    }
    if constexpr (TRANSFORM) {
        #pragma unroll
        for (int k = 0; k < DIN; k++)
            xin[k] = fmaxf(fmaf(di, xin[k], bprev[k]), 0.0f);
    }

    float acc[DOUT];
    #pragma unroll
    for (int j = 0; j < DOUT; j++) acc[j] = 0.0f;
    #pragma unroll
    for (int k = 0; k < DIN; k++) {
        float xk = xin[k];
        #pragma unroll
        for (int j = 0; j < DOUT; j++) acc[j] = fmaf(xk, sW[k * DOUT + j], acc[j]);
    }

    float4* hp4 = (float4*)(hp + (size_t)i * DOUT);
    #pragma unroll
    for (int j4 = 0; j4 < DOUT / 4; j4++)
        hp4[j4] = make_float4(acc[4 * j4] * di, acc[4 * j4 + 1] * di,
                              acc[4 * j4 + 2] * di, acc[4 * j4 + 3] * di);
}

// ---- atomic-free gather: agg[i] = hp[i] + sum_{e: dst=i} hp[src[e]] -------

template<int D, bool FINAL>
__global__ __launch_bounds__(THREADS)
void k_gather(const int* __restrict__ rowptr, const int* __restrict__ csr,
              const float* __restrict__ hp, float* __restrict__ outp,
              const float* __restrict__ dinv, const float* __restrict__ bias,
              int n) {
    int tid  = blockIdx.x * THREADS + threadIdx.x;
    int row  = tid / D;
    int lane = tid & (D - 1);
    if (row >= n) return;
    int base = (threadIdx.x & 63) & ~(D - 1);

    int beg = rowptr[row];
    int end = rowptr[row + 1];

    float a0 = hp[(size_t)row * D + lane];  // self-loop
    float a1 = 0.f, a2 = 0.f, a3 = 0.f;

    int e = beg;
    for (; e + D <= end; e += D) {
        int s = csr[e + lane];
        #pragma unroll
        for (int k = 0; k < D; k += 4) {
            int s0 = __shfl(s, base + k + 0, 64);
            int s1 = __shfl(s, base + k + 1, 64);
            int s2 = __shfl(s, base + k + 2, 64);
            int s3 = __shfl(s, base + k + 3, 64);
            a0 += hp[(size_t)s0 * D + lane];
            a1 += hp[(size_t)s1 * D + lane];
            a2 += hp[(size_t)s2 * D + lane];
            a3 += hp[(size_t)s3 * D + lane];
        }
    }
    if (e < end) {
        int idx = e + lane;
        int s = (idx < end) ? csr[idx] : 0;
        int cnt = end - e;
        for (int k = 0; k < cnt; k++) {
            int sk = __shfl(s, base + k, 64);
            a0 += hp[(size_t)sk * D + lane];
        }
    }
    float acc = (a0 + a1) + (a2 + a3);

    if constexpr (FINAL) {
        outp[(size_t)row * D + lane] = fmaf(dinv[row], acc, bias[lane]);
    } else {
        outp[(size_t)row * D + lane] = acc;
    }
}

// ---- fallback scatter path (workspace too small for CSR) ------------------

template<int DOUT>
__global__ __launch_bounds__(THREADS)
void k_agg(const int* __restrict__ src, const int* __restrict__ dst,
           const float* __restrict__ hp, float* __restrict__ agg, int ecount) {
    int i = blockIdx.x * THREADS + threadIdx.x;
    if (i >= ecount) return;
    const float4* s4 = (const float4*)(hp + (size_t)src[i] * DOUT);
    float* dp = agg + (size_t)dst[i] * DOUT;
    #pragma unroll
    for (int j4 = 0; j4 < DOUT / 4; j4++) {
        float4 v = s4[j4];
        atomicAdd(dp + 4 * j4 + 0, v.x);
        atomicAdd(dp + 4 * j4 + 1, v.y);
        atomicAdd(dp + 4 * j4 + 2, v.z);
        atomicAdd(dp + 4 * j4 + 3, v.w);
    }
}

__global__ __launch_bounds__(THREADS)
void k_selfinit(const float* __restrict__ hp, float* __restrict__ agg, int n16) {
    int i = blockIdx.x * THREADS + threadIdx.x;
    if (i < n16) agg[i] = hp[i];
}

__global__ __launch_bounds__(THREADS)
void k_final(const float* __restrict__ agg, const float* __restrict__ b4,
             const float* __restrict__ dinv, float* __restrict__ out, int n) {
    int i = blockIdx.x * THREADS + threadIdx.x;
    if (i >= n) return;
    float di = dinv[i];
    float4 a = *(const float4*)(agg + (size_t)i * 4);
    *(float4*)(out + (size_t)i * 4) =
        make_float4(fmaf(di, a.x, b4[0]), fmaf(di, a.y, b4[1]),
                    fmaf(di, a.z, b4[2]), fmaf(di, a.w, b4[3]));
}

// ---------------------------------------------------------------------------

extern "C" void kernel_launch(void* const* d_in, const int* in_sizes, int n_in,
                              void* d_out, int out_size, void* d_ws, size_t ws_size,
                              hipStream_t stream) {
    const float* x   = (const float*)d_in[0];
    const int*   ei  = (const int*)d_in[1];   // int32 per harness conversion
    const float* W1  = (const float*)d_in[2];
    const float* b1  = (const float*)d_in[3];
    const float* W2  = (const float*)d_in[4];
    const float* b2  = (const float*)d_in[5];
    const float* W3  = (const float*)d_in[6];
    const float* b3  = (const float*)d_in[7];
    const float* W4  = (const float*)d_in[8];
    const float* b4  = (const float*)d_in[9];
    float*       out = (float*)d_out;

    const int N = in_sizes[0] / 34;
    const int E = in_sizes[1] / 2;
    const int* src = ei;
    const int* dst = ei + E;

    char* ws = (char*)d_ws;
    size_t off = 0;
    auto alloc = [&](size_t bytes) -> void* {
        void* p = ws + off;
        off += (bytes + 255) & ~(size_t)255;
        return p;
    };
    int*   deg    = (int*)  alloc((size_t)N * 4);
    float* dinv   = (float*)alloc((size_t)N * 4);
    float* bufA   = (float*)alloc((size_t)N * 16 * 4);
    float* bufB   = (float*)alloc((size_t)N * 16 * 4);
    float* bufC   = (float*)alloc((size_t)N * 16 * 4);
    int*   rowptr = (int*)  alloc((size_t)(N + 1) * 4);
    int*   cursor = (int*)  alloc((size_t)N * 4);
    const int nb  = (N + THREADS - 1) / THREADS;
    int*   bsum   = (int*)  alloc((size_t)nb * 4);
    int*   csr    = (int*)  alloc((size_t)E * 4);
    bool   use_csr = off <= ws_size;
    int*   rank   = (int*)  alloc((size_t)E * 4);
    bool   use_rank = off <= ws_size;

    // vector edge passes need 16B-aligned src/dst and E%4==0
    bool vec_ok = use_rank && (E % EPT == 0) &&
                  (((uintptr_t)src & 15) == 0) && (((uintptr_t)dst & 15) == 0);

    const int gN  = (N + THREADS - 1) / THREADS;
    const int gE  = (E + THREADS - 1) / THREADS;
    const int gE4 = (E / EPT + THREADS - 1) / THREADS;
    const int g16 = (int)(((size_t)N * 16 + THREADS - 1) / THREADS);
    const int g4  = (int)(((size_t)N * 4 + THREADS - 1) / THREADS);

    // ---- degree (+rank) ----
    k_zero<<<gN, THREADS, 0, stream>>>(deg, N);
    if (vec_ok) {
        k_count_rank<<<gE4, THREADS, 0, stream>>>(dst, deg, rank, E);
    } else {
        k_count_deg<<<gE, THREADS, 0, stream>>>(dst, deg, E);
    }
    k_dinv<<<gN, THREADS, 0, stream>>>(deg, dinv, N);

    if (use_csr) {
        // ---- rowptr scan + CSR fill ----
        k_scan1<<<nb, THREADS, 0, stream>>>(deg, rowptr, bsum, N);
        k_scan2<<<1, 1024, 0, stream>>>(bsum, nb);
        k_scan3<<<nb, THREADS, 0, stream>>>(rowptr, bsum, cursor, N, E);
        if (vec_ok) {
            k_fill_rank<<<gE4, THREADS, 0, stream>>>(src, dst, rank, rowptr, csr, E);
        } else {
            k_fill_cursor<<<gE, THREADS, 0, stream>>>(src, dst, cursor, csr, E);
        }

        // ---- layers ----
        k_layer<34, 16, false><<<gN, THREADS, 0, stream>>>(x, W1, nullptr, dinv, bufA, N);
        k_gather<16, false><<<g16, THREADS, 0, stream>>>(rowptr, csr, bufA, bufB, nullptr, nullptr, N);

        k_layer<16, 16, true><<<gN, THREADS, 0, stream>>>(bufB, W2, b1, dinv, bufC, N);
        k_gather<16, false><<<g16, THREADS, 0, stream>>>(rowptr, csr, bufC, bufA, nullptr, nullptr, N);

        k_layer<16, 16, true><<<gN, THREADS, 0, stream>>>(bufA, W3, b2, dinv, bufB, N);
        k_gather<16, false><<<g16, THREADS, 0, stream>>>(rowptr, csr, bufB, bufC, nullptr, nullptr, N);

        k_layer<16, 4, true><<<gN, THREADS, 0, stream>>>(bufC, W4, b3, dinv, bufA, N);
        k_gather<4, true><<<g4, THREADS, 0, stream>>>(rowptr, csr, bufA, out, dinv, b4, N);
        return;
    }

    // ---- fallback: atomic scatter path ----
    k_layer<34, 16, false><<<gN, THREADS, 0, stream>>>(x, W1, nullptr, dinv, bufA, N);
    k_selfinit<<<g16, THREADS, 0, stream>>>(bufA, bufB, N * 16);
    k_agg<16><<<gE, THREADS, 0, stream>>>(src, dst, bufA, bufB, E);

    k_layer<16, 16, true><<<gN, THREADS, 0, stream>>>(bufB, W2, b1, dinv, bufC, N);
    k_selfinit<<<g16, THREADS, 0, stream>>>(bufC, bufA, N * 16);
    k_agg<16><<<gE, THREADS, 0, stream>>>(src, dst, bufC, bufA, E);

    k_layer<16, 16, true><<<gN, THREADS, 0, stream>>>(bufA, W3, b2, dinv, bufB, N);
    k_selfinit<<<g16, THREADS, 0, stream>>>(bufB, bufC, N * 16);
    k_agg<16><<<gE, THREADS, 0, stream>>>(src, dst, bufB, bufC, E);

    k_layer<16, 4, true><<<gN, THREADS, 0, stream>>>(bufC, W4, b3, dinv, bufA, N);
    k_selfinit<<<g4, THREADS, 0, stream>>>(bufA, bufB, N * 4);
    k_agg<4><<<gE, THREADS, 0, stream>>>(src, dst, bufA, bufB, E);

    k_final<<<gN, THREADS, 0, stream>>>(bufB, b4, dinv, out, N);
}

// Round 5
// 472.282 us; speedup vs baseline: 36.0725x; 1.3040x over previous
//
#include <hip/hip_runtime.h>
#include <hip/hip_bf16.h>

// 4-layer GCN, N=100000, E=6400000, dims 34->16->16->16->4.
//
// out[i] = b + dinv[i] * sum_{e: dst=i} dinv[src]*h[src]  (incl. self-loop)
// => hp = dinv*(x@W); agg[i] = hp[i] + sum_{in-edges} hp[src]; out = dinv*agg + b.
//
// Round-5: CSR built via atomic-free two-level counting sort:
//   A) per-block LDS histogram over coarse buckets (dst>>7)
//   B) column scan of partials (in-place) + bucket-base scan
//   C) scatter edges grouped-by-bucket via LDS cursors (cache-local stores)
//   D) per-bucket block: LDS node-histogram -> rowptr/dinv, LDS-cursor csr fill
// This removes all 12.8M global atomics and the 8x random-store write
// amplification that dominated rounds 3-4.

static constexpr int THREADS = 256;
static constexpr int BSHIFT  = 7;     // nodes per bucket = 128
static constexpr int NPB     = 128;
static constexpr int MAXB    = 1024;  // max buckets supported by LDS arrays
static constexpr int NCHUNK  = 512;   // blocks in edge-streaming passes

// ============================ fast path =====================================

// ---- pass A: per-block bucket histogram ----
__global__ __launch_bounds__(THREADS)
void k_hist(const int* __restrict__ dst, int* __restrict__ hist_part,
            int e, int nbkt, int chunk) {
    __shared__ int h[MAXB];
    for (int t = threadIdx.x; t < nbkt; t += THREADS) h[t] = 0;
    __syncthreads();
    int beg = blockIdx.x * chunk;
    int end = min(e, beg + chunk);
    for (int base = beg; base < end; base += THREADS * 4) {
        int i = base + (int)threadIdx.x * 4;
        if (i + 4 <= end) {
            int4 d = *(const int4*)(dst + i);
            atomicAdd(&h[d.x >> BSHIFT], 1);
            atomicAdd(&h[d.y >> BSHIFT], 1);
            atomicAdd(&h[d.z >> BSHIFT], 1);
            atomicAdd(&h[d.w >> BSHIFT], 1);
        } else {
            for (int k = i; k < end; k++) atomicAdd(&h[dst[k] >> BSHIFT], 1);
        }
    }
    __syncthreads();
    for (int t = threadIdx.x; t < nbkt; t += THREADS)
        hist_part[(size_t)blockIdx.x * nbkt + t] = h[t];
}

// ---- pass B1: per-bucket column scan over NCHUNK partials (in-place) ----
__global__ __launch_bounds__(NCHUNK)
void k_colscan(int* __restrict__ hist_part, int* __restrict__ btot, int nbkt) {
    __shared__ int s[NCHUNK];
    int b = blockIdx.x;
    int v = hist_part[(size_t)threadIdx.x * nbkt + b];
    s[threadIdx.x] = v;
    __syncthreads();
    for (int ofs = 1; ofs < NCHUNK; ofs <<= 1) {
        int t = (threadIdx.x >= ofs) ? s[threadIdx.x - ofs] : 0;
        __syncthreads();
        s[threadIdx.x] += t;
        __syncthreads();
    }
    hist_part[(size_t)threadIdx.x * nbkt + b] = s[threadIdx.x] - v;  // exclusive
    if (threadIdx.x == NCHUNK - 1) btot[b] = s[NCHUNK - 1];
}

// ---- pass B2: exclusive scan of bucket totals ----
__global__ __launch_bounds__(1024)
void k_scan_b(const int* __restrict__ btot, int* __restrict__ bbase,
              int nbkt, int e) {
    __shared__ int s[1024];
    int v = (threadIdx.x < nbkt) ? btot[threadIdx.x] : 0;
    s[threadIdx.x] = v;
    __syncthreads();
    for (int ofs = 1; ofs < 1024; ofs <<= 1) {
        int t = (threadIdx.x >= ofs) ? s[threadIdx.x - ofs] : 0;
        __syncthreads();
        s[threadIdx.x] += t;
        __syncthreads();
    }
    if (threadIdx.x < nbkt) bbase[threadIdx.x] = s[threadIdx.x] - v;
    if (threadIdx.x == 0) bbase[nbkt] = e;
}

// ---- pass C: scatter edges grouped by bucket ----
__global__ __launch_bounds__(THREADS)
void k_scatter_bkt(const int* __restrict__ src, const int* __restrict__ dst,
                   const int* __restrict__ offs_part, const int* __restrict__ bbase,
                   int* __restrict__ gsrc, unsigned char* __restrict__ gdl,
                   int e, int nbkt, int chunk) {
    __shared__ int curs[MAXB];
    for (int t = threadIdx.x; t < nbkt; t += THREADS)
        curs[t] = bbase[t] + offs_part[(size_t)blockIdx.x * nbkt + t];
    __syncthreads();
    int beg = blockIdx.x * chunk;
    int end = min(e, beg + chunk);
    for (int base = beg; base < end; base += THREADS * 4) {
        int i = base + (int)threadIdx.x * 4;
        if (i + 4 <= end) {
            int4 sv = *(const int4*)(src + i);
            int4 dv = *(const int4*)(dst + i);
            int p0 = atomicAdd(&curs[dv.x >> BSHIFT], 1);
            int p1 = atomicAdd(&curs[dv.y >> BSHIFT], 1);
            int p2 = atomicAdd(&curs[dv.z >> BSHIFT], 1);
            int p3 = atomicAdd(&curs[dv.w >> BSHIFT], 1);
            gsrc[p0] = sv.x; gdl[p0] = (unsigned char)(dv.x & (NPB - 1));
            gsrc[p1] = sv.y; gdl[p1] = (unsigned char)(dv.y & (NPB - 1));
            gsrc[p2] = sv.z; gdl[p2] = (unsigned char)(dv.z & (NPB - 1));
            gsrc[p3] = sv.w; gdl[p3] = (unsigned char)(dv.w & (NPB - 1));
        } else {
            for (int k = i; k < end; k++) {
                int d = dst[k];
                int p = atomicAdd(&curs[d >> BSHIFT], 1);
                gsrc[p] = src[k]; gdl[p] = (unsigned char)(d & (NPB - 1));
            }
        }
    }
}

// ---- pass D: per-bucket node histogram + scan -> rowptr/dinv, csr fill ----
__global__ __launch_bounds__(THREADS)
void k_bucket_build(const int* __restrict__ gsrc, const unsigned char* __restrict__ gdl,
                    const int* __restrict__ bbase, int* __restrict__ rowptr,
                    float* __restrict__ dinv, int* __restrict__ csr,
                    int n, int nbkt) {
    __shared__ int hist[NPB];
    __shared__ int scn[NPB];
    int b = blockIdx.x;
    int node0 = b << BSHIFT;
    int nnodes = min(NPB, n - node0);
    int ebeg = bbase[b];
    int eend = bbase[b + 1];
    int tid = threadIdx.x;

    if (tid < NPB) hist[tid] = 0;
    __syncthreads();
    for (int i = ebeg + tid; i < eend; i += THREADS)
        atomicAdd(&hist[gdl[i]], 1);
    __syncthreads();
    // Hillis-Steele inclusive scan of hist into scn
    if (tid < NPB) scn[tid] = hist[tid];
    __syncthreads();
    for (int ofs = 1; ofs < NPB; ofs <<= 1) {
        int t = (tid < NPB && tid >= ofs) ? scn[tid - ofs] : 0;
        __syncthreads();
        if (tid < NPB) scn[tid] += t;
        __syncthreads();
    }
    if (tid < nnodes) {
        int h = hist[tid];
        int excl = scn[tid] - h;
        rowptr[node0 + tid] = ebeg + excl;
        dinv[node0 + tid] = 1.0f / sqrtf((float)(h + 1));
    }
    if (b == nbkt - 1 && tid == 0) rowptr[n] = eend;
    // cursors
    if (tid < NPB) scn[tid] = ebeg + (scn[tid] - hist[tid]);
    __syncthreads();
    for (int i = ebeg + tid; i < eend; i += THREADS) {
        int dl = gdl[i];
        int pos = atomicAdd(&scn[dl], 1);
        csr[pos] = gsrc[i];
    }
}

// ====================== shared compute kernels ==============================

template<int DIN, int DOUT, bool TRANSFORM>
__global__ __launch_bounds__(THREADS)
void k_layer(const float* __restrict__ in, const float* __restrict__ W,
             const float* __restrict__ bprev, const float* __restrict__ dinv,
             float* __restrict__ hp, int n) {
    __shared__ float sW[DIN * DOUT];
    for (int t = threadIdx.x; t < DIN * DOUT; t += THREADS) sW[t] = W[t];
    __syncthreads();

    int i = blockIdx.x * THREADS + threadIdx.x;
    if (i >= n) return;
    float di = dinv[i];

    float xin[DIN];
    if constexpr (DIN % 4 == 0) {
        const float4* in4 = (const float4*)(in + (size_t)i * DIN);
        #pragma unroll
        for (int k4 = 0; k4 < DIN / 4; k4++) {
            float4 v = in4[k4];
            xin[4 * k4 + 0] = v.x; xin[4 * k4 + 1] = v.y;
            xin[4 * k4 + 2] = v.z; xin[4 * k4 + 3] = v.w;
        }
    } else {
        #pragma unroll
        for (int k = 0; k < DIN; k++) xin[k] = in[(size_t)i * DIN + k];
    }
    if constexpr (TRANSFORM) {
        #pragma unroll
        for (int k = 0; k < DIN; k++)
            xin[k] = fmaxf(fmaf(di, xin[k], bprev[k]), 0.0f);
    }

    float acc[DOUT];
    #pragma unroll
    for (int j = 0; j < DOUT; j++) acc[j] = 0.0f;
    #pragma unroll
    for (int k = 0; k < DIN; k++) {
        float xk = xin[k];
        #pragma unroll
        for (int j = 0; j < DOUT; j++) acc[j] = fmaf(xk, sW[k * DOUT + j], acc[j]);
    }

    float4* hp4 = (float4*)(hp + (size_t)i * DOUT);
    #pragma unroll
    for (int j4 = 0; j4 < DOUT / 4; j4++)
        hp4[j4] = make_float4(acc[4 * j4] * di, acc[4 * j4 + 1] * di,
                              acc[4 * j4 + 2] * di, acc[4 * j4 + 3] * di);
}

template<int D, bool FINAL>
__global__ __launch_bounds__(THREADS)
void k_gather(const int* __restrict__ rowptr, const int* __restrict__ csr,
              const float* __restrict__ hp, float* __restrict__ outp,
              const float* __restrict__ dinv, const float* __restrict__ bias,
              int n) {
    int tid  = blockIdx.x * THREADS + threadIdx.x;
    int row  = tid / D;
    int lane = tid & (D - 1);
    if (row >= n) return;
    int base = (threadIdx.x & 63) & ~(D - 1);

    int beg = rowptr[row];
    int end = rowptr[row + 1];

    float a0 = hp[(size_t)row * D + lane];  // self-loop
    float a1 = 0.f, a2 = 0.f, a3 = 0.f;

    int e = beg;
    for (; e + D <= end; e += D) {
        int s = csr[e + lane];
        #pragma unroll
        for (int k = 0; k < D; k += 4) {
            int s0 = __shfl(s, base + k + 0, 64);
            int s1 = __shfl(s, base + k + 1, 64);
            int s2 = __shfl(s, base + k + 2, 64);
            int s3 = __shfl(s, base + k + 3, 64);
            a0 += hp[(size_t)s0 * D + lane];
            a1 += hp[(size_t)s1 * D + lane];
            a2 += hp[(size_t)s2 * D + lane];
            a3 += hp[(size_t)s3 * D + lane];
        }
    }
    if (e < end) {
        int idx = e + lane;
        int s = (idx < end) ? csr[idx] : 0;
        int cnt = end - e;
        for (int k = 0; k < cnt; k++) {
            int sk = __shfl(s, base + k, 64);
            a0 += hp[(size_t)sk * D + lane];
        }
    }
    float acc = (a0 + a1) + (a2 + a3);

    if constexpr (FINAL) {
        outp[(size_t)row * D + lane] = fmaf(dinv[row], acc, bias[lane]);
    } else {
        outp[(size_t)row * D + lane] = acc;
    }
}

// ========================= fallback path kernels ============================

__global__ __launch_bounds__(THREADS)
void k_zero(int* __restrict__ p, int n) {
    int i = blockIdx.x * THREADS + threadIdx.x;
    if (i < n) p[i] = 0;
}

__global__ __launch_bounds__(THREADS)
void k_count_deg(const int* __restrict__ dst, int* __restrict__ deg, int e) {
    int i = blockIdx.x * THREADS + threadIdx.x;
    if (i >= e) return;
    atomicAdd(&deg[dst[i]], 1);
}

__global__ __launch_bounds__(THREADS)
void k_dinv(const int* __restrict__ deg, float* __restrict__ dinv, int n) {
    int i = blockIdx.x * THREADS + threadIdx.x;
    if (i < n) dinv[i] = 1.0f / sqrtf((float)(deg[i] + 1));
}

__global__ __launch_bounds__(THREADS)
void k_scan1(const int* __restrict__ deg, int* __restrict__ rowptr,
             int* __restrict__ bsum, int n) {
    __shared__ int s[THREADS];
    int i = blockIdx.x * THREADS + threadIdx.x;
    int v = (i < n) ? deg[i] : 0;
    s[threadIdx.x] = v;
    __syncthreads();
    for (int ofs = 1; ofs < THREADS; ofs <<= 1) {
        int t = (threadIdx.x >= ofs) ? s[threadIdx.x - ofs] : 0;
        __syncthreads();
        s[threadIdx.x] += t;
        __syncthreads();
    }
    if (i < n) rowptr[i] = s[threadIdx.x] - v;
    if (threadIdx.x == THREADS - 1) bsum[blockIdx.x] = s[THREADS - 1];
}

__global__ __launch_bounds__(1024)
void k_scan2(int* __restrict__ bsum, int nb) {
    __shared__ int s[1024];
    int v = (threadIdx.x < nb) ? bsum[threadIdx.x] : 0;
    s[threadIdx.x] = v;
    __syncthreads();
    for (int ofs = 1; ofs < 1024; ofs <<= 1) {
        int t = (threadIdx.x >= ofs) ? s[threadIdx.x - ofs] : 0;
        __syncthreads();
        s[threadIdx.x] += t;
        __syncthreads();
    }
    if (threadIdx.x < nb) bsum[threadIdx.x] = s[threadIdx.x] - v;
}

__global__ __launch_bounds__(THREADS)
void k_scan3(int* __restrict__ rowptr, const int* __restrict__ bsum,
             int* __restrict__ cursor, int n, int e) {
    int i = blockIdx.x * THREADS + threadIdx.x;
    if (i < n) {
        int r = rowptr[i] + bsum[blockIdx.x];
        rowptr[i] = r;
        cursor[i] = r;
    }
    if (i == 0) rowptr[n] = e;
}

__global__ __launch_bounds__(THREADS)
void k_fill_cursor(const int* __restrict__ src, const int* __restrict__ dst,
                   int* __restrict__ cursor, int* __restrict__ csr, int e) {
    int i = blockIdx.x * THREADS + threadIdx.x;
    if (i >= e) return;
    int pos = atomicAdd(&cursor[dst[i]], 1);
    csr[pos] = src[i];
}

// ---------------------------------------------------------------------------

extern "C" void kernel_launch(void* const* d_in, const int* in_sizes, int n_in,
                              void* d_out, int out_size, void* d_ws, size_t ws_size,
                              hipStream_t stream) {
    const float* x   = (const float*)d_in[0];
    const int*   ei  = (const int*)d_in[1];   // int32 per harness conversion
    const float* W1  = (const float*)d_in[2];
    const float* b1  = (const float*)d_in[3];
    const float* W2  = (const float*)d_in[4];
    const float* b2  = (const float*)d_in[5];
    const float* W3  = (const float*)d_in[6];
    const float* b3  = (const float*)d_in[7];
    const float* W4  = (const float*)d_in[8];
    const float* b4  = (const float*)d_in[9];
    float*       out = (float*)d_out;

    const int N = in_sizes[0] / 34;
    const int E = in_sizes[1] / 2;
    const int* src = ei;
    const int* dst = ei + E;

    const int gN  = (N + THREADS - 1) / THREADS;
    const int g16 = (int)(((size_t)N * 16 + THREADS - 1) / THREADS);
    const int g4  = (int)(((size_t)N * 4 + THREADS - 1) / THREADS);

    const int nbkt  = (N + NPB - 1) >> BSHIFT;
    const int chunk = (((E + NCHUNK - 1) / NCHUNK) + 3) & ~3;

    // ---- fast-path carve ----
    {
        char* ws = (char*)d_ws;
        size_t off = 0;
        auto alloc = [&](size_t bytes) -> void* {
            void* p = ws + off;
            off += (bytes + 255) & ~(size_t)255;
            return p;
        };
        float* dinv   = (float*)alloc((size_t)N * 4);
        float* bufA   = (float*)alloc((size_t)N * 16 * 4);
        float* bufB   = (float*)alloc((size_t)N * 16 * 4);
        int*   rowptr = (int*)  alloc((size_t)(N + 1) * 4);
        int*   csr    = (int*)  alloc((size_t)E * 4);
        int*   gsrc   = (int*)  alloc((size_t)E * 4);
        unsigned char* gdl = (unsigned char*)alloc((size_t)E);
        int*   offsp  = (int*)  alloc((size_t)NCHUNK * nbkt * 4);
        int*   btot   = (int*)  alloc((size_t)nbkt * 4);
        int*   bbase  = (int*)  alloc((size_t)(nbkt + 1) * 4);

        bool aligned16 = (((uintptr_t)src & 15) == 0) && (((uintptr_t)dst & 15) == 0);
        bool fast_ok = (nbkt <= MAXB) && (off <= ws_size) && aligned16;

        if (fast_ok) {
            // ---- counting-sort CSR build (atomic-free at device scope) ----
            k_hist       <<<NCHUNK, THREADS, 0, stream>>>(dst, offsp, E, nbkt, chunk);
            k_colscan    <<<nbkt, NCHUNK, 0, stream>>>(offsp, btot, nbkt);
            k_scan_b     <<<1, 1024, 0, stream>>>(btot, bbase, nbkt, E);
            k_scatter_bkt<<<NCHUNK, THREADS, 0, stream>>>(src, dst, offsp, bbase,
                                                          gsrc, gdl, E, nbkt, chunk);
            k_bucket_build<<<nbkt, THREADS, 0, stream>>>(gsrc, gdl, bbase, rowptr,
                                                         dinv, csr, N, nbkt);

            // ---- layers (two rotating buffers) ----
            k_layer<34, 16, false><<<gN, THREADS, 0, stream>>>(x, W1, nullptr, dinv, bufA, N);
            k_gather<16, false><<<g16, THREADS, 0, stream>>>(rowptr, csr, bufA, bufB, nullptr, nullptr, N);

            k_layer<16, 16, true><<<gN, THREADS, 0, stream>>>(bufB, W2, b1, dinv, bufA, N);
            k_gather<16, false><<<g16, THREADS, 0, stream>>>(rowptr, csr, bufA, bufB, nullptr, nullptr, N);

            k_layer<16, 16, true><<<gN, THREADS, 0, stream>>>(bufB, W3, b2, dinv, bufA, N);
            k_gather<16, false><<<g16, THREADS, 0, stream>>>(rowptr, csr, bufA, bufB, nullptr, nullptr, N);

            k_layer<16, 4, true><<<gN, THREADS, 0, stream>>>(bufB, W4, b3, dinv, bufA, N);
            k_gather<4, true><<<g4, THREADS, 0, stream>>>(rowptr, csr, bufA, out, dinv, b4, N);
            return;
        }
    }

    // ---- fallback: round-4 cursor-atomic CSR path ----
    {
        char* ws = (char*)d_ws;
        size_t off = 0;
        auto alloc = [&](size_t bytes) -> void* {
            void* p = ws + off;
            off += (bytes + 255) & ~(size_t)255;
            return p;
        };
        int*   deg    = (int*)  alloc((size_t)N * 4);
        float* dinv   = (float*)alloc((size_t)N * 4);
        float* bufA   = (float*)alloc((size_t)N * 16 * 4);
        float* bufB   = (float*)alloc((size_t)N * 16 * 4);
        int*   rowptr = (int*)  alloc((size_t)(N + 1) * 4);
        int*   cursor = (int*)  alloc((size_t)N * 4);
        const int nb  = (N + THREADS - 1) / THREADS;
        int*   bsum   = (int*)  alloc((size_t)nb * 4);
        int*   csr    = (int*)  alloc((size_t)E * 4);

        const int gE = (E + THREADS - 1) / THREADS;

        k_zero<<<gN, THREADS, 0, stream>>>(deg, N);
        k_count_deg<<<gE, THREADS, 0, stream>>>(dst, deg, E);
        k_dinv<<<gN, THREADS, 0, stream>>>(deg, dinv, N);
        k_scan1<<<nb, THREADS, 0, stream>>>(deg, rowptr, bsum, N);
        k_scan2<<<1, 1024, 0, stream>>>(bsum, nb);
        k_scan3<<<nb, THREADS, 0, stream>>>(rowptr, bsum, cursor, N, E);
        k_fill_cursor<<<gE, THREADS, 0, stream>>>(src, dst, cursor, csr, E);

        k_layer<34, 16, false><<<gN, THREADS, 0, stream>>>(x, W1, nullptr, dinv, bufA, N);
        k_gather<16, false><<<g16, THREADS, 0, stream>>>(rowptr, csr, bufA, bufB, nullptr, nullptr, N);

        k_layer<16, 16, true><<<gN, THREADS, 0, stream>>>(bufB, W2, b1, dinv, bufA, N);
        k_gather<16, false><<<g16, THREADS, 0, stream>>>(rowptr, csr, bufA, bufB, nullptr, nullptr, N);

        k_layer<16, 16, true><<<gN, THREADS, 0, stream>>>(bufB, W3, b2, dinv, bufA, N);
        k_gather<16, false><<<g16, THREADS, 0, stream>>>(rowptr, csr, bufA, bufB, nullptr, nullptr, N);

        k_layer<16, 4, true><<<gN, THREADS, 0, stream>>>(bufB, W4, b3, dinv, bufA, N);
        k_gather<4, true><<<g4, THREADS, 0, stream>>>(rowptr, csr, bufA, out, dinv, b4, N);
    }
}

// Round 6
// 382.930 us; speedup vs baseline: 44.4895x; 1.2333x over previous
//
#include <hip/hip_runtime.h>
#include <hip/hip_bf16.h>

// 4-layer GCN, N=100000, E=6400000, dims 34->16->16->16->4.
//
// out[i] = b + dinv[i] * sum_{e: dst=i} dinv[src]*h[src]  (incl. self-loop)
// => hp = dinv*(x@W); agg[i] = hp[i] + sum_{in-edges} hp[src]; out = dinv*agg + b.
//
// Round-6: scatter write-amplification fix.
//  - buckets of 256 nodes (BSHIFT=8, nbkt=391): (block,bucket) runs = ~32 edges
//  - pack (src<<8)|(dst&255) into ONE int -> one 128 B run per (block,bucket)
//    instead of separate 64 B gsrc + 16 B gdl runs (was ~9x amplification)
//  - EPT=8 for more independent cursor-atomic->store chains (MLP)

static constexpr int THREADS = 256;
static constexpr int BSHIFT  = 8;     // nodes per bucket = 256
static constexpr int NPB     = 256;
static constexpr int MAXB    = 512;   // LDS array bound (nbkt <= MAXB)
static constexpr int NCHUNK  = 512;   // blocks in edge-streaming passes
static constexpr int EPT     = 8;     // edges per thread in streaming passes

// ============================ fast path =====================================

// ---- pass A: per-block bucket histogram ----
__global__ __launch_bounds__(THREADS)
void k_hist(const int* __restrict__ dst, int* __restrict__ hist_part,
            int e, int nbkt, int chunk) {
    __shared__ int h[MAXB];
    for (int t = threadIdx.x; t < nbkt; t += THREADS) h[t] = 0;
    __syncthreads();
    int beg = blockIdx.x * chunk;
    int end = min(e, beg + chunk);
    for (int base = beg; base < end; base += THREADS * EPT) {
        int i = base + (int)threadIdx.x * EPT;
        if (i + EPT <= end) {
            int4 d0 = *(const int4*)(dst + i);
            int4 d1 = *(const int4*)(dst + i + 4);
            atomicAdd(&h[d0.x >> BSHIFT], 1);
            atomicAdd(&h[d0.y >> BSHIFT], 1);
            atomicAdd(&h[d0.z >> BSHIFT], 1);
            atomicAdd(&h[d0.w >> BSHIFT], 1);
            atomicAdd(&h[d1.x >> BSHIFT], 1);
            atomicAdd(&h[d1.y >> BSHIFT], 1);
            atomicAdd(&h[d1.z >> BSHIFT], 1);
            atomicAdd(&h[d1.w >> BSHIFT], 1);
        } else {
            for (int k = i; k < end; k++) atomicAdd(&h[dst[k] >> BSHIFT], 1);
        }
    }
    __syncthreads();
    for (int t = threadIdx.x; t < nbkt; t += THREADS)
        hist_part[(size_t)blockIdx.x * nbkt + t] = h[t];
}

// ---- pass B1: per-bucket column scan over NCHUNK partials (in-place) ----
__global__ __launch_bounds__(NCHUNK)
void k_colscan(int* __restrict__ hist_part, int* __restrict__ btot, int nbkt) {
    __shared__ int s[NCHUNK];
    int b = blockIdx.x;
    int v = hist_part[(size_t)threadIdx.x * nbkt + b];
    s[threadIdx.x] = v;
    __syncthreads();
    for (int ofs = 1; ofs < NCHUNK; ofs <<= 1) {
        int t = (threadIdx.x >= ofs) ? s[threadIdx.x - ofs] : 0;
        __syncthreads();
        s[threadIdx.x] += t;
        __syncthreads();
    }
    hist_part[(size_t)threadIdx.x * nbkt + b] = s[threadIdx.x] - v;  // exclusive
    if (threadIdx.x == NCHUNK - 1) btot[b] = s[NCHUNK - 1];
}

// ---- pass B2: exclusive scan of bucket totals ----
__global__ __launch_bounds__(1024)
void k_scan_b(const int* __restrict__ btot, int* __restrict__ bbase,
              int nbkt, int e) {
    __shared__ int s[1024];
    int v = (threadIdx.x < nbkt) ? btot[threadIdx.x] : 0;
    s[threadIdx.x] = v;
    __syncthreads();
    for (int ofs = 1; ofs < 1024; ofs <<= 1) {
        int t = (threadIdx.x >= ofs) ? s[threadIdx.x - ofs] : 0;
        __syncthreads();
        s[threadIdx.x] += t;
        __syncthreads();
    }
    if (threadIdx.x < nbkt) bbase[threadIdx.x] = s[threadIdx.x] - v;
    if (threadIdx.x == 0) bbase[nbkt] = e;
}

// ---- pass C: scatter edges grouped by bucket, packed (src<<8)|dlocal ----
__global__ __launch_bounds__(THREADS)
void k_scatter_bkt(const int* __restrict__ src, const int* __restrict__ dst,
                   const int* __restrict__ offs_part, const int* __restrict__ bbase,
                   int* __restrict__ gpack, int e, int nbkt, int chunk) {
    __shared__ int curs[MAXB];
    for (int t = threadIdx.x; t < nbkt; t += THREADS)
        curs[t] = bbase[t] + offs_part[(size_t)blockIdx.x * nbkt + t];
    __syncthreads();
    int beg = blockIdx.x * chunk;
    int end = min(e, beg + chunk);
    for (int base = beg; base < end; base += THREADS * EPT) {
        int i = base + (int)threadIdx.x * EPT;
        if (i + EPT <= end) {
            int4 s0 = *(const int4*)(src + i);
            int4 s1 = *(const int4*)(src + i + 4);
            int4 d0 = *(const int4*)(dst + i);
            int4 d1 = *(const int4*)(dst + i + 4);
            int p0 = atomicAdd(&curs[d0.x >> BSHIFT], 1);
            int p1 = atomicAdd(&curs[d0.y >> BSHIFT], 1);
            int p2 = atomicAdd(&curs[d0.z >> BSHIFT], 1);
            int p3 = atomicAdd(&curs[d0.w >> BSHIFT], 1);
            int p4 = atomicAdd(&curs[d1.x >> BSHIFT], 1);
            int p5 = atomicAdd(&curs[d1.y >> BSHIFT], 1);
            int p6 = atomicAdd(&curs[d1.z >> BSHIFT], 1);
            int p7 = atomicAdd(&curs[d1.w >> BSHIFT], 1);
            gpack[p0] = (s0.x << BSHIFT) | (d0.x & (NPB - 1));
            gpack[p1] = (s0.y << BSHIFT) | (d0.y & (NPB - 1));
            gpack[p2] = (s0.z << BSHIFT) | (d0.z & (NPB - 1));
            gpack[p3] = (s0.w << BSHIFT) | (d0.w & (NPB - 1));
            gpack[p4] = (s1.x << BSHIFT) | (d1.x & (NPB - 1));
            gpack[p5] = (s1.y << BSHIFT) | (d1.y & (NPB - 1));
            gpack[p6] = (s1.z << BSHIFT) | (d1.z & (NPB - 1));
            gpack[p7] = (s1.w << BSHIFT) | (d1.w & (NPB - 1));
        } else {
            for (int k = i; k < end; k++) {
                int d = dst[k];
                int p = atomicAdd(&curs[d >> BSHIFT], 1);
                gpack[p] = (src[k] << BSHIFT) | (d & (NPB - 1));
            }
        }
    }
}

// ---- pass D: per-bucket node histogram + scan -> rowptr/dinv, csr fill ----
__global__ __launch_bounds__(THREADS)
void k_bucket_build(const int* __restrict__ gpack, const int* __restrict__ bbase,
                    int* __restrict__ rowptr, float* __restrict__ dinv,
                    int* __restrict__ csr, int n, int nbkt) {
    __shared__ int hist[NPB];
    __shared__ int scn[NPB];
    int b = blockIdx.x;
    int node0 = b << BSHIFT;
    int nnodes = min(NPB, n - node0);
    int ebeg = bbase[b];
    int eend = bbase[b + 1];
    int tid = threadIdx.x;

    hist[tid] = 0;
    __syncthreads();
    for (int i = ebeg + tid; i < eend; i += THREADS)
        atomicAdd(&hist[gpack[i] & (NPB - 1)], 1);
    __syncthreads();
    // Hillis-Steele inclusive scan of hist into scn
    scn[tid] = hist[tid];
    __syncthreads();
    for (int ofs = 1; ofs < NPB; ofs <<= 1) {
        int t = (tid >= ofs) ? scn[tid - ofs] : 0;
        __syncthreads();
        scn[tid] += t;
        __syncthreads();
    }
    if (tid < nnodes) {
        int h = hist[tid];
        int excl = scn[tid] - h;
        rowptr[node0 + tid] = ebeg + excl;
        dinv[node0 + tid] = 1.0f / sqrtf((float)(h + 1));
    }
    if (b == nbkt - 1 && tid == 0) rowptr[n] = eend;
    // cursors
    scn[tid] = ebeg + (scn[tid] - hist[tid]);
    __syncthreads();
    for (int i = ebeg + tid; i < eend; i += THREADS) {
        int g = gpack[i];
        int pos = atomicAdd(&scn[g & (NPB - 1)], 1);
        csr[pos] = g >> BSHIFT;
    }
}

// ====================== shared compute kernels ==============================

template<int DIN, int DOUT, bool TRANSFORM>
__global__ __launch_bounds__(THREADS)
void k_layer(const float* __restrict__ in, const float* __restrict__ W,
             const float* __restrict__ bprev, const float* __restrict__ dinv,
             float* __restrict__ hp, int n) {
    __shared__ float sW[DIN * DOUT];
    for (int t = threadIdx.x; t < DIN * DOUT; t += THREADS) sW[t] = W[t];
    __syncthreads();

    int i = blockIdx.x * THREADS + threadIdx.x;
    if (i >= n) return;
    float di = dinv[i];

    float xin[DIN];
    if constexpr (DIN % 4 == 0) {
        const float4* in4 = (const float4*)(in + (size_t)i * DIN);
        #pragma unroll
        for (int k4 = 0; k4 < DIN / 4; k4++) {
            float4 v = in4[k4];
            xin[4 * k4 + 0] = v.x; xin[4 * k4 + 1] = v.y;
            xin[4 * k4 + 2] = v.z; xin[4 * k4 + 3] = v.w;
        }
    } else {
        #pragma unroll
        for (int k = 0; k < DIN; k++) xin[k] = in[(size_t)i * DIN + k];
    }
    if constexpr (TRANSFORM) {
        #pragma unroll
        for (int k = 0; k < DIN; k++)
            xin[k] = fmaxf(fmaf(di, xin[k], bprev[k]), 0.0f);
    }

    float acc[DOUT];
    #pragma unroll
    for (int j = 0; j < DOUT; j++) acc[j] = 0.0f;
    #pragma unroll
    for (int k = 0; k < DIN; k++) {
        float xk = xin[k];
        #pragma unroll
        for (int j = 0; j < DOUT; j++) acc[j] = fmaf(xk, sW[k * DOUT + j], acc[j]);
    }

    float4* hp4 = (float4*)(hp + (size_t)i * DOUT);
    #pragma unroll
    for (int j4 = 0; j4 < DOUT / 4; j4++)
        hp4[j4] = make_float4(acc[4 * j4] * di, acc[4 * j4 + 1] * di,
                              acc[4 * j4 + 2] * di, acc[4 * j4 + 3] * di);
}

template<int D, bool FINAL>
__global__ __launch_bounds__(THREADS)
void k_gather(const int* __restrict__ rowptr, const int* __restrict__ csr,
              const float* __restrict__ hp, float* __restrict__ outp,
              const float* __restrict__ dinv, const float* __restrict__ bias,
              int n) {
    int tid  = blockIdx.x * THREADS + threadIdx.x;
    int row  = tid / D;
    int lane = tid & (D - 1);
    if (row >= n) return;
    int base = (threadIdx.x & 63) & ~(D - 1);

    int beg = rowptr[row];
    int end = rowptr[row + 1];

    float a0 = hp[(size_t)row * D + lane];  // self-loop
    float a1 = 0.f, a2 = 0.f, a3 = 0.f;

    int e = beg;
    for (; e + D <= end; e += D) {
        int s = csr[e + lane];
        #pragma unroll
        for (int k = 0; k < D; k += 4) {
            int s0 = __shfl(s, base + k + 0, 64);
            int s1 = __shfl(s, base + k + 1, 64);
            int s2 = __shfl(s, base + k + 2, 64);
            int s3 = __shfl(s, base + k + 3, 64);
            a0 += hp[(size_t)s0 * D + lane];
            a1 += hp[(size_t)s1 * D + lane];
            a2 += hp[(size_t)s2 * D + lane];
            a3 += hp[(size_t)s3 * D + lane];
        }
    }
    if (e < end) {
        int idx = e + lane;
        int s = (idx < end) ? csr[idx] : 0;
        int cnt = end - e;
        for (int k = 0; k < cnt; k++) {
            int sk = __shfl(s, base + k, 64);
            a0 += hp[(size_t)sk * D + lane];
        }
    }
    float acc = (a0 + a1) + (a2 + a3);

    if constexpr (FINAL) {
        outp[(size_t)row * D + lane] = fmaf(dinv[row], acc, bias[lane]);
    } else {
        outp[(size_t)row * D + lane] = acc;
    }
}

// ========================= fallback path kernels ============================

__global__ __launch_bounds__(THREADS)
void k_zero(int* __restrict__ p, int n) {
    int i = blockIdx.x * THREADS + threadIdx.x;
    if (i < n) p[i] = 0;
}

__global__ __launch_bounds__(THREADS)
void k_count_deg(const int* __restrict__ dst, int* __restrict__ deg, int e) {
    int i = blockIdx.x * THREADS + threadIdx.x;
    if (i >= e) return;
    atomicAdd(&deg[dst[i]], 1);
}

__global__ __launch_bounds__(THREADS)
void k_dinv(const int* __restrict__ deg, float* __restrict__ dinv, int n) {
    int i = blockIdx.x * THREADS + threadIdx.x;
    if (i < n) dinv[i] = 1.0f / sqrtf((float)(deg[i] + 1));
}

__global__ __launch_bounds__(THREADS)
void k_scan1(const int* __restrict__ deg, int* __restrict__ rowptr,
             int* __restrict__ bsum, int n) {
    __shared__ int s[THREADS];
    int i = blockIdx.x * THREADS + threadIdx.x;
    int v = (i < n) ? deg[i] : 0;
    s[threadIdx.x] = v;
    __syncthreads();
    for (int ofs = 1; ofs < THREADS; ofs <<= 1) {
        int t = (threadIdx.x >= ofs) ? s[threadIdx.x - ofs] : 0;
        __syncthreads();
        s[threadIdx.x] += t;
        __syncthreads();
    }
    if (i < n) rowptr[i] = s[threadIdx.x] - v;
    if (threadIdx.x == THREADS - 1) bsum[blockIdx.x] = s[THREADS - 1];
}

__global__ __launch_bounds__(1024)
void k_scan2(int* __restrict__ bsum, int nb) {
    __shared__ int s[1024];
    int v = (threadIdx.x < nb) ? bsum[threadIdx.x] : 0;
    s[threadIdx.x] = v;
    __syncthreads();
    for (int ofs = 1; ofs < 1024; ofs <<= 1) {
        int t = (threadIdx.x >= ofs) ? s[threadIdx.x - ofs] : 0;
        __syncthreads();
        s[threadIdx.x] += t;
        __syncthreads();
    }
    if (threadIdx.x < nb) bsum[threadIdx.x] = s[threadIdx.x] - v;
}

__global__ __launch_bounds__(THREADS)
void k_scan3(int* __restrict__ rowptr, const int* __restrict__ bsum,
             int* __restrict__ cursor, int n, int e) {
    int i = blockIdx.x * THREADS + threadIdx.x;
    if (i < n) {
        int r = rowptr[i] + bsum[blockIdx.x];
        rowptr[i] = r;
        cursor[i] = r;
    }
    if (i == 0) rowptr[n] = e;
}

__global__ __launch_bounds__(THREADS)
void k_fill_cursor(const int* __restrict__ src, const int* __restrict__ dst,
                   int* __restrict__ cursor, int* __restrict__ csr, int e) {
    int i = blockIdx.x * THREADS + threadIdx.x;
    if (i >= e) return;
    int pos = atomicAdd(&cursor[dst[i]], 1);
    csr[pos] = src[i];
}

// ---------------------------------------------------------------------------

extern "C" void kernel_launch(void* const* d_in, const int* in_sizes, int n_in,
                              void* d_out, int out_size, void* d_ws, size_t ws_size,
                              hipStream_t stream) {
    const float* x   = (const float*)d_in[0];
    const int*   ei  = (const int*)d_in[1];   // int32 per harness conversion
    const float* W1  = (const float*)d_in[2];
    const float* b1  = (const float*)d_in[3];
    const float* W2  = (const float*)d_in[4];
    const float* b2  = (const float*)d_in[5];
    const float* W3  = (const float*)d_in[6];
    const float* b3  = (const float*)d_in[7];
    const float* W4  = (const float*)d_in[8];
    const float* b4  = (const float*)d_in[9];
    float*       out = (float*)d_out;

    const int N = in_sizes[0] / 34;
    const int E = in_sizes[1] / 2;
    const int* src = ei;
    const int* dst = ei + E;

    const int gN  = (N + THREADS - 1) / THREADS;
    const int g16 = (int)(((size_t)N * 16 + THREADS - 1) / THREADS);
    const int g4  = (int)(((size_t)N * 4 + THREADS - 1) / THREADS);

    const int nbkt  = (N + NPB - 1) >> BSHIFT;
    const int chunk = (((E + NCHUNK - 1) / NCHUNK) + EPT - 1) & ~(EPT - 1);

    // ---- fast-path carve ----
    {
        char* ws = (char*)d_ws;
        size_t off = 0;
        auto alloc = [&](size_t bytes) -> void* {
            void* p = ws + off;
            off += (bytes + 255) & ~(size_t)255;
            return p;
        };
        float* dinv   = (float*)alloc((size_t)N * 4);
        float* bufA   = (float*)alloc((size_t)N * 16 * 4);
        float* bufB   = (float*)alloc((size_t)N * 16 * 4);
        int*   rowptr = (int*)  alloc((size_t)(N + 1) * 4);
        int*   csr    = (int*)  alloc((size_t)E * 4);
        int*   gpack  = (int*)  alloc((size_t)E * 4);
        int*   offsp  = (int*)  alloc((size_t)NCHUNK * nbkt * 4);
        int*   btot   = (int*)  alloc((size_t)nbkt * 4);
        int*   bbase  = (int*)  alloc((size_t)(nbkt + 1) * 4);

        bool aligned16 = (((uintptr_t)src & 15) == 0) && (((uintptr_t)dst & 15) == 0);
        bool fast_ok = (nbkt <= MAXB) && (off <= ws_size) && aligned16 &&
                       (N <= (1 << (31 - BSHIFT)));  // src<<8 must not overflow

        if (fast_ok) {
            // ---- counting-sort CSR build (atomic-free at device scope) ----
            k_hist       <<<NCHUNK, THREADS, 0, stream>>>(dst, offsp, E, nbkt, chunk);
            k_colscan    <<<nbkt, NCHUNK, 0, stream>>>(offsp, btot, nbkt);
            k_scan_b     <<<1, 1024, 0, stream>>>(btot, bbase, nbkt, E);
            k_scatter_bkt<<<NCHUNK, THREADS, 0, stream>>>(src, dst, offsp, bbase,
                                                          gpack, E, nbkt, chunk);
            k_bucket_build<<<nbkt, THREADS, 0, stream>>>(gpack, bbase, rowptr,
                                                         dinv, csr, N, nbkt);

            // ---- layers (two rotating buffers) ----
            k_layer<34, 16, false><<<gN, THREADS, 0, stream>>>(x, W1, nullptr, dinv, bufA, N);
            k_gather<16, false><<<g16, THREADS, 0, stream>>>(rowptr, csr, bufA, bufB, nullptr, nullptr, N);

            k_layer<16, 16, true><<<gN, THREADS, 0, stream>>>(bufB, W2, b1, dinv, bufA, N);
            k_gather<16, false><<<g16, THREADS, 0, stream>>>(rowptr, csr, bufA, bufB, nullptr, nullptr, N);

            k_layer<16, 16, true><<<gN, THREADS, 0, stream>>>(bufB, W3, b2, dinv, bufA, N);
            k_gather<16, false><<<g16, THREADS, 0, stream>>>(rowptr, csr, bufA, bufB, nullptr, nullptr, N);

            k_layer<16, 4, true><<<gN, THREADS, 0, stream>>>(bufB, W4, b3, dinv, bufA, N);
            k_gather<4, true><<<g4, THREADS, 0, stream>>>(rowptr, csr, bufA, out, dinv, b4, N);
            return;
        }
    }

    // ---- fallback: cursor-atomic CSR path ----
    {
        char* ws = (char*)d_ws;
        size_t off = 0;
        auto alloc = [&](size_t bytes) -> void* {
            void* p = ws + off;
            off += (bytes + 255) & ~(size_t)255;
            return p;
        };
        int*   deg    = (int*)  alloc((size_t)N * 4);
        float* dinv   = (float*)alloc((size_t)N * 4);
        float* bufA   = (float*)alloc((size_t)N * 16 * 4);
        float* bufB   = (float*)alloc((size_t)N * 16 * 4);
        int*   rowptr = (int*)  alloc((size_t)(N + 1) * 4);
        int*   cursor = (int*)  alloc((size_t)N * 4);
        const int nb  = (N + THREADS - 1) / THREADS;
        int*   bsum   = (int*)  alloc((size_t)nb * 4);
        int*   csr    = (int*)  alloc((size_t)E * 4);

        const int gE = (E + THREADS - 1) / THREADS;

        k_zero<<<gN, THREADS, 0, stream>>>(deg, N);
        k_count_deg<<<gE, THREADS, 0, stream>>>(dst, deg, E);
        k_dinv<<<gN, THREADS, 0, stream>>>(deg, dinv, N);
        k_scan1<<<nb, THREADS, 0, stream>>>(deg, rowptr, bsum, N);
        k_scan2<<<1, 1024, 0, stream>>>(bsum, nb);
        k_scan3<<<nb, THREADS, 0, stream>>>(rowptr, bsum, cursor, N, E);
        k_fill_cursor<<<gE, THREADS, 0, stream>>>(src, dst, cursor, csr, E);

        k_layer<34, 16, false><<<gN, THREADS, 0, stream>>>(x, W1, nullptr, dinv, bufA, N);
        k_gather<16, false><<<g16, THREADS, 0, stream>>>(rowptr, csr, bufA, bufB, nullptr, nullptr, N);

        k_layer<16, 16, true><<<gN, THREADS, 0, stream>>>(bufB, W2, b1, dinv, bufA, N);
        k_gather<16, false><<<g16, THREADS, 0, stream>>>(rowptr, csr, bufA, bufB, nullptr, nullptr, N);

        k_layer<16, 16, true><<<gN, THREADS, 0, stream>>>(bufB, W3, b2, dinv, bufA, N);
        k_gather<16, false><<<g16, THREADS, 0, stream>>>(rowptr, csr, bufA, bufB, nullptr, nullptr, N);

        k_layer<16, 4, true><<<gN, THREADS, 0, stream>>>(bufB, W4, b3, dinv, bufA, N);
        k_gather<4, true><<<g4, THREADS, 0, stream>>>(rowptr, csr, bufA, out, dinv, b4, N);
    }
}